// Round 2
// baseline (50719.379 us; speedup 1.0000x reference)
//
#include <hip/hip_runtime.h>

#define TSTEPS 1920
#define NB 128
#define HIDN 256
#define LATN 128
#define EPSF 1e-5f

__device__ __forceinline__ float fsig(float x) {
    float e = __expf(-fabsf(x));
    float s = 1.f / (1.f + e);
    return x >= 0.f ? s : 1.f - s;
}
__device__ __forceinline__ float ftanh(float x) {
    float e = __expf(-2.f * fabsf(x));
    float r = (1.f - e) / (1.f + e);
    return x >= 0.f ? r : -r;
}
__device__ __forceinline__ float fleaky(float x) { return x > 0.f ? x : 0.2f * x; }

// ---- K0: pack W [N][KA+KB] (optionally two sources) -> out[k4][n][4] f32 ----
__global__ void pack4T(const float* __restrict__ A, const float* __restrict__ Bsrc,
                       int N, int KA, int KB, float* __restrict__ out) {
    int e = blockIdx.x * 256 + threadIdx.x;
    int Ktot = KA + KB;
    if (e >= N * Ktot) return;
    int j = e & 3;
    int rest = e >> 2;
    int n = rest % N;
    int k4 = rest / N;
    int k = 4 * k4 + j;
    float v = (k < KA) ? A[n * KA + k] : Bsrc[n * KB + (k - KA)];
    out[e] = v;
}

// ---- K1: embedding + np MLP + LN + leaky -> x_const [B][512] ----
__global__ void np_head(const float* __restrict__ z, const int* __restrict__ labels,
                        const float* __restrict__ emb_W, const float* __restrict__ np_W,
                        const float* __restrict__ np_b, const float* __restrict__ np_g,
                        const float* __restrict__ np_be, float* __restrict__ x_const) {
    int b = blockIdx.x;
    int j = threadIdx.x;  // 0..255
    __shared__ float xc[LATN + HIDN];
    __shared__ float red[8];
    int lab = labels[b];
    if (j < LATN) xc[j] = z[b * LATN + j];
    float e = emb_W[lab * HIDN + j];
    xc[LATN + j] = e;
    __syncthreads();
    float d = np_b[j];
    for (int k = 0; k < LATN + HIDN; ++k) d += xc[k] * np_W[j * (LATN + HIDN) + k];
    int lane = j & 63, wv = j >> 6;
    float s = d, s2 = d * d;
    for (int o = 1; o < 64; o <<= 1) { s += __shfl_xor(s, o); s2 += __shfl_xor(s2, o); }
    if (lane == 0) { red[wv] = s; red[4 + wv] = s2; }
    __syncthreads();
    float S = red[0] + red[1] + red[2] + red[3];
    float S2 = red[4] + red[5] + red[6] + red[7];
    float m = S * (1.f / 256.f);
    float var = S2 * (1.f / 256.f) - m * m;
    float h = fleaky((d - m) * rsqrtf(var + EPSF) * np_g[j] + np_be[j]);
    x_const[b * 512 + j] = h;
    x_const[b * 512 + 256 + j] = e;
}

// ---- K2: xw0[b][g] = bih0+bhh0 + x_const[b] . Wih0[g] ----
__global__ void __launch_bounds__(1024) xw0_kernel(const float* __restrict__ x_const,
                                                   const float4* __restrict__ Wih0T4,
                                                   const float* __restrict__ bih0,
                                                   const float* __restrict__ bhh0,
                                                   float* __restrict__ xw0) {
    int b = blockIdx.x;
    int g = threadIdx.x;  // 0..1023
    __shared__ float xc[512];
    if (g < 512) xc[g] = x_const[b * 512 + g];
    __syncthreads();
    const float4* xc4 = (const float4*)xc;
    float4 acc = {0.f, 0.f, 0.f, 0.f};
#pragma unroll 8
    for (int k4 = 0; k4 < 128; ++k4) {
        float4 w = Wih0T4[k4 * 1024 + g];
        float4 x = xc4[k4];
        acc.x = fmaf(w.x, x.x, acc.x);
        acc.y = fmaf(w.y, x.y, acc.y);
        acc.z = fmaf(w.z, x.z, acc.z);
        acc.w = fmaf(w.w, x.w, acc.w);
    }
    xw0[b * 1024 + g] = bih0[g] + bhh0[g] + ((acc.x + acc.y) + (acc.z + acc.w));
}

// ---- K3: fused 2-layer LSTM + per-step head -> base, hsum. 2 rows/block ----
__global__ void __launch_bounds__(1024) lstm_kernel(
    const float4* __restrict__ Whh0T4, const float4* __restrict__ W1catT4,
    const float4* __restrict__ sW1T4, const float* __restrict__ xw0,
    const float* __restrict__ bih1, const float* __restrict__ bhh1,
    const float* __restrict__ sb1, const float* __restrict__ sg,
    const float* __restrict__ sbe, const float* __restrict__ sW2,
    const float* __restrict__ sb2, float* __restrict__ base_out,
    float* __restrict__ hsum_out) {
    int b = blockIdx.x;
    int rowA = 2 * b, rowB = 2 * b + 1;
    int tid = threadIdx.x;  // 0..1023
    int lane = tid & 63, wv = tid >> 6;
    __shared__ float hcatA[512], hcatB[512];   // [0..255]=h0, [256..511]=h1
    __shared__ float gatesA[1024], gatesB[1024];
    __shared__ float red[16];
    float xwA = xw0[rowA * 1024 + tid];
    float xwB = xw0[rowB * 1024 + tid];
    float b1 = bih1[tid] + bhh1[tid];
    // persistent cell state: tid<512 -> unit u=tid&255, row=tid>>8
    float c0 = 0.f, c1 = 0.f, hs = 0.f;
    // head consts: tid<256 -> j=tid&127, hrow=tid>>7
    float sb1_j = 0.f, sg_j = 0.f, sbe_j = 0.f, sW2_j = 0.f;
    if (tid < 256) {
        int j = tid & 127;
        sb1_j = sb1[j]; sg_j = sg[j]; sbe_j = sbe[j]; sW2_j = sW2[j];
    }
    float sb2_v = sb2[0];
    if (tid < 512) { hcatA[tid] = 0.f; hcatB[tid] = 0.f; }
    __syncthreads();
    const float4* hA4 = (const float4*)hcatA;
    const float4* hB4 = (const float4*)hcatB;

#pragma unroll 1
    for (int t = 0; t < TSTEPS; ++t) {
        // --- MV0: gates = xw0 + Whh0 @ h0 (both rows) ---
        {
            float4 aA = {0.f, 0.f, 0.f, 0.f}, aB = {0.f, 0.f, 0.f, 0.f};
#pragma unroll 8
            for (int k4 = 0; k4 < 64; ++k4) {
                float4 w = Whh0T4[k4 * 1024 + tid];
                float4 ha = hA4[k4];
                float4 hb = hB4[k4];
                aA.x = fmaf(w.x, ha.x, aA.x); aA.y = fmaf(w.y, ha.y, aA.y);
                aA.z = fmaf(w.z, ha.z, aA.z); aA.w = fmaf(w.w, ha.w, aA.w);
                aB.x = fmaf(w.x, hb.x, aB.x); aB.y = fmaf(w.y, hb.y, aB.y);
                aB.z = fmaf(w.z, hb.z, aB.z); aB.w = fmaf(w.w, hb.w, aB.w);
            }
            gatesA[tid] = xwA + ((aA.x + aA.y) + (aA.z + aA.w));
            gatesB[tid] = xwB + ((aB.x + aB.y) + (aB.z + aB.w));
        }
        __syncthreads();
        // --- UPD0 ---
        if (tid < 512) {
            int u = tid & 255;
            const float* gz = (tid >> 8) ? gatesB : gatesA;
            float i_ = gz[u], f_ = gz[256 + u], g_ = gz[512 + u], o_ = gz[768 + u];
            c0 = fsig(f_) * c0 + fsig(i_) * ftanh(g_);
            float h = fsig(o_) * ftanh(c0);
            ((tid >> 8) ? hcatB : hcatA)[u] = h;
        }
        __syncthreads();
        // --- MV1: gates = b1 + [Wih1|Whh1] @ [h0;h1] ---
        {
            float4 aA = {0.f, 0.f, 0.f, 0.f}, aB = {0.f, 0.f, 0.f, 0.f};
#pragma unroll 8
            for (int k4 = 0; k4 < 128; ++k4) {
                float4 w = W1catT4[k4 * 1024 + tid];
                float4 ha = hA4[k4];
                float4 hb = hB4[k4];
                aA.x = fmaf(w.x, ha.x, aA.x); aA.y = fmaf(w.y, ha.y, aA.y);
                aA.z = fmaf(w.z, ha.z, aA.z); aA.w = fmaf(w.w, ha.w, aA.w);
                aB.x = fmaf(w.x, hb.x, aB.x); aB.y = fmaf(w.y, hb.y, aB.y);
                aB.z = fmaf(w.z, hb.z, aB.z); aB.w = fmaf(w.w, hb.w, aB.w);
            }
            gatesA[tid] = b1 + ((aA.x + aA.y) + (aA.z + aA.w));
            gatesB[tid] = b1 + ((aB.x + aB.y) + (aB.z + aB.w));
        }
        __syncthreads();
        // --- UPD1 ---
        if (tid < 512) {
            int u = tid & 255;
            const float* gz = (tid >> 8) ? gatesB : gatesA;
            float i_ = gz[u], f_ = gz[256 + u], g_ = gz[512 + u], o_ = gz[768 + u];
            c1 = fsig(f_) * c1 + fsig(i_) * ftanh(g_);
            float h = fsig(o_) * ftanh(c1);
            hs += h;
            ((tid >> 8) ? hcatB : hcatA)[256 + u] = h;
        }
        __syncthreads();
        // --- HEAD: s1 = sb1 + sW1 @ h1; LN(128); leaky; dot sW2; tanh ---
        float s1 = 0.f;
        if (tid < 256) {
            int j = tid & 127;
            const float4* hp = (tid >> 7) ? hB4 : hA4;
            float4 a = {0.f, 0.f, 0.f, 0.f};
#pragma unroll 8
            for (int k4 = 0; k4 < 64; ++k4) {
                float4 w = sW1T4[k4 * 128 + j];
                float4 h = hp[64 + k4];
                a.x = fmaf(w.x, h.x, a.x); a.y = fmaf(w.y, h.y, a.y);
                a.z = fmaf(w.z, h.z, a.z); a.w = fmaf(w.w, h.w, a.w);
            }
            s1 = sb1_j + ((a.x + a.y) + (a.z + a.w));
        }
        float ssum = s1, ssq = s1 * s1;
        for (int o = 1; o < 64; o <<= 1) { ssum += __shfl_xor(ssum, o); ssq += __shfl_xor(ssq, o); }
        if (lane == 0 && wv < 4) { red[wv] = ssum; red[4 + wv] = ssq; }
        __syncthreads();
        float qtotA, qtotB;
        {
            float q = 0.f;
            if (tid < 256) {
                int hrow = tid >> 7;
                float m = (red[2 * hrow] + red[2 * hrow + 1]) * (1.f / 128.f);
                float var = (red[4 + 2 * hrow] + red[4 + 2 * hrow + 1]) * (1.f / 128.f) - m * m;
                float rstd = rsqrtf(var + EPSF);
                float p = fleaky((s1 - m) * rstd * sg_j + sbe_j);
                q = p * sW2_j;
            }
            for (int o = 1; o < 64; o <<= 1) q += __shfl_xor(q, o);
            if (lane == 0 && wv < 4) red[8 + wv] = q;
        }
        __syncthreads();
        if (tid == 0) base_out[rowA * TSTEPS + t] = ftanh(red[8] + red[9] + sb2_v);
        else if (tid == 64) base_out[rowB * TSTEPS + t] = ftanh(red[10] + red[11] + sb2_v);
        __syncthreads();
    }
    if (tid < 512) {
        int u = tid & 255, row = tid >> 8;
        hsum_out[(2 * b + row) * HIDN + u] = hs;
    }
}

// ---- K4: op head + oscillator + smoothing + label select ----
__global__ void out_kernel(const float* __restrict__ hsum, const float* __restrict__ oW1,
                           const float* __restrict__ ob1, const float* __restrict__ og,
                           const float* __restrict__ obe, const float* __restrict__ oW2,
                           const float* __restrict__ ob2, const float* __restrict__ base,
                           const int* __restrict__ labels, const float* __restrict__ stress_w,
                           const float* __restrict__ amu_w, const float* __restrict__ amu_b,
                           float* __restrict__ out) {
    int b = blockIdx.x;
    int tid = threadIdx.x;  // 0..255
    int lane = tid & 63, wv = tid >> 6;
    __shared__ float havg[256];
    __shared__ float red[8];
    __shared__ float params[3];
    __shared__ float e_row[TSTEPS];
    havg[tid] = hsum[b * 256 + tid] * (1.f / (float)TSTEPS);
    __syncthreads();
    float d1 = 0.f;
    if (tid < 128) {
        d1 = ob1[tid];
        for (int k = 0; k < 256; ++k) d1 += havg[k] * oW1[tid * 256 + k];
    }
    float s = d1, s2 = d1 * d1;
    for (int o = 1; o < 64; o <<= 1) { s += __shfl_xor(s, o); s2 += __shfl_xor(s2, o); }
    if (lane == 0 && wv < 2) { red[wv] = s; red[2 + wv] = s2; }
    __syncthreads();
    float m = (red[0] + red[1]) * (1.f / 128.f);
    float var = (red[2] + red[3]) * (1.f / 128.f) - m * m;
    float rstd = rsqrtf(var + EPSF);
    float p = 0.f;
    if (tid < 128) p = fleaky((d1 - m) * rstd * og[tid] + obe[tid]);
    float q0 = tid < 128 ? p * oW2[0 * 128 + tid] : 0.f;
    float q1 = tid < 128 ? p * oW2[1 * 128 + tid] : 0.f;
    float q2 = tid < 128 ? p * oW2[2 * 128 + tid] : 0.f;
    for (int o = 1; o < 64; o <<= 1) {
        q0 += __shfl_xor(q0, o); q1 += __shfl_xor(q1, o); q2 += __shfl_xor(q2, o);
    }
    __syncthreads();
    if (lane == 0 && wv < 2) { red[wv] = q0; red[2 + wv] = q1; red[4 + wv] = q2; }
    __syncthreads();
    if (tid == 0) {
        float op0 = red[0] + red[1] + ob2[0];
        float op1 = red[2] + red[3] + ob2[1];
        float op2 = red[4] + red[5] + ob2[2];
        params[0] = 0.23f + 0.04f * ftanh(op0);
        params[1] = 2.0f + 1.5f * ftanh(op1);
        params[2] = 3.14159265358979f * fsig(op2);
    }
    __syncthreads();
    float freq = params[0], amp = params[1], ph = params[2];
    for (int t = tid; t < TSTEPS; t += 256) {
        float x = freq * ((float)TSTEPS * (float)t / (float)(TSTEPS - 1));
        x -= floorf(x);  // range reduction in revolutions
        float osc = amp * __sinf(6.28318530717958647f * x + ph);
        e_row[t] = 0.6f * base[b * TSTEPS + t] + 0.4f * osc;
    }
    __syncthreads();
    int lab = labels[b];
    float sw = stress_w[0];
    float w0 = amu_w[0], w1 = amu_w[1], w2 = amu_w[2], ab = amu_b[0];
    for (int t = tid; t < TSTEPS; t += 256) {
        float e = e_row[t];
        float r;
        if (lab == 1) r = e;
        else if (lab == 2) r = sw * e;
        else if (lab == 3) {
            float em = t > 0 ? e_row[t - 1] : 0.f;
            float ep = t < TSTEPS - 1 ? e_row[t + 1] : 0.f;
            r = w0 * em + w1 * e + w2 * ep + ab;
        } else r = 0.f;
        out[b * TSTEPS + t] = r;
    }
}

extern "C" void kernel_launch(void* const* d_in, const int* in_sizes, int n_in,
                              void* d_out, int out_size, void* d_ws, size_t ws_size,
                              hipStream_t stream) {
    (void)in_sizes; (void)n_in; (void)out_size; (void)ws_size;
    const float* z      = (const float*)d_in[0];
    const int* labels   = (const int*)d_in[1];
    const float* emb_W  = (const float*)d_in[2];
    const float* np_W   = (const float*)d_in[3];
    const float* np_b   = (const float*)d_in[4];
    const float* np_g   = (const float*)d_in[5];
    const float* np_be  = (const float*)d_in[6];
    const float* Wih0   = (const float*)d_in[7];
    const float* Whh0   = (const float*)d_in[8];
    const float* bih0   = (const float*)d_in[9];
    const float* bhh0   = (const float*)d_in[10];
    const float* Wih1   = (const float*)d_in[11];
    const float* Whh1   = (const float*)d_in[12];
    const float* bih1   = (const float*)d_in[13];
    const float* bhh1   = (const float*)d_in[14];
    const float* oW1    = (const float*)d_in[15];
    const float* ob1    = (const float*)d_in[16];
    const float* og     = (const float*)d_in[17];
    const float* obe    = (const float*)d_in[18];
    const float* oW2    = (const float*)d_in[19];
    const float* ob2    = (const float*)d_in[20];
    const float* sW1    = (const float*)d_in[21];
    const float* sb1    = (const float*)d_in[22];
    const float* sg     = (const float*)d_in[23];
    const float* sbe    = (const float*)d_in[24];
    const float* sW2    = (const float*)d_in[25];
    const float* sb2    = (const float*)d_in[26];
    const float* stressw= (const float*)d_in[27];
    const float* amu_w  = (const float*)d_in[28];
    const float* amu_b  = (const float*)d_in[29];
    float* out = (float*)d_out;

    uint8_t* ws = (uint8_t*)d_ws;
    size_t off = 0;
    float* Whh0T4 = (float*)(ws + off); off += (size_t)1024 * 256 * 4;        // 1MB
    float* W1catT4= (float*)(ws + off); off += (size_t)1024 * 512 * 4;        // 2MB
    float* Wih0T4 = (float*)(ws + off); off += (size_t)1024 * 512 * 4;        // 2MB
    float* sW1T4  = (float*)(ws + off); off += (size_t)128 * 256 * 4;         // 128KB
    float* x_const= (float*)(ws + off); off += (size_t)NB * 512 * 4;          // 256KB
    float* xw0    = (float*)(ws + off); off += (size_t)NB * 1024 * 4;         // 512KB
    float* hsum   = (float*)(ws + off); off += (size_t)NB * 256 * 4;          // 128KB
    float* basef  = (float*)(ws + off); off += (size_t)NB * TSTEPS * 4;       // 960KB

    pack4T<<<(1024 * 256 + 255) / 256, 256, 0, stream>>>(Whh0, nullptr, 1024, 256, 0, Whh0T4);
    pack4T<<<(1024 * 512 + 255) / 256, 256, 0, stream>>>(Wih1, Whh1, 1024, 256, 256, W1catT4);
    pack4T<<<(1024 * 512 + 255) / 256, 256, 0, stream>>>(Wih0, nullptr, 1024, 512, 0, Wih0T4);
    pack4T<<<(128 * 256 + 255) / 256, 256, 0, stream>>>(sW1, nullptr, 128, 256, 0, sW1T4);

    np_head<<<NB, 256, 0, stream>>>(z, labels, emb_W, np_W, np_b, np_g, np_be, x_const);
    xw0_kernel<<<NB, 1024, 0, stream>>>(x_const, (const float4*)Wih0T4, bih0, bhh0, xw0);
    lstm_kernel<<<NB / 2, 1024, 0, stream>>>((const float4*)Whh0T4, (const float4*)W1catT4,
                                             (const float4*)sW1T4, xw0, bih1, bhh1,
                                             sb1, sg, sbe, sW2, sb2, basef, hsum);
    out_kernel<<<NB, 256, 0, stream>>>(hsum, oW1, ob1, og, obe, oW2, ob2, basef, labels,
                                       stressw, amu_w, amu_b, out);
}